// Round 3
// baseline (127.797 us; speedup 1.0000x reference)
//
#include <hip/hip_runtime.h>
#include <hip/hip_cooperative_groups.h>

namespace cg = cooperative_groups;

#define NBINS 100
#define NATOM 1024
#define NBLK  256
#define PI_F 3.14159265358979323846f

// ---------------- fused cooperative kernel ----------------
// Phase 1: 256 blocks x 1024 threads; block handles rows i0..i0+3, thread owns
// column j. Windowed Gaussian smear into LDS histogram (16 bins around
// floor(d/DB); omitted tail < 2e-11 per pair). Partials -> ws[b*256 + p].
// grid.sync(). Phase 2: block 0 reduces 256 partials/bin, normalizes, writes
// count[100] | bins[101] | rdf[100].
__global__ __launch_bounds__(1024) void rdf_all(const float* __restrict__ xyz,
                                                const float* __restrict__ cell,
                                                float* __restrict__ out,
                                                float* __restrict__ ws) {
    const float cx = cell[0], cy = cell[1], cz = cell[2];
    const float hx = 0.5f * cx, hy = 0.5f * cy, hz = 0.5f * cz;
    const float coeff  = -0.5f * (99.0f * 99.0f) / (5.0f * 5.0f);  // -0.5/width^2
    const float cutsq  = 5.5f * 5.5f;
    const float DB     = 5.0f / 99.0f;
    const float INV_DB = 99.0f / 5.0f;

    __shared__ float sh[NBINS];
    __shared__ float tot[NBINS];
    __shared__ float wsum[2];

    if (threadIdx.x < NBINS) sh[threadIdx.x] = 0.0f;
    __syncthreads();

    // thread owns atom j (coalesced load)
    const int j = threadIdx.x;
    const float xj = xyz[3 * j + 0];
    const float yj = xyz[3 * j + 1];
    const float zj = xyz[3 * j + 2];

    const int i0 = blockIdx.x * (NATOM / NBLK);
#pragma unroll
    for (int r = 0; r < NATOM / NBLK; ++r) {
        const int i = i0 + r;                 // block-uniform -> scalar loads
        const float xi = xyz[3 * i + 0];
        const float yi = xyz[3 * i + 1];
        const float zi = xyz[3 * i + 2];
        float dx = xj - xi;                   // dvec = xyz[j] - xyz[i]
        float dy = yj - yi;
        float dz = zj - zi;
        // minimum-image PBC, exact replication of reference shift rule
        dx += (dx < -hx ? cx : 0.0f) - (dx >= hx ? cx : 0.0f);
        dy += (dy < -hy ? cy : 0.0f) - (dy >= hy ? cy : 0.0f);
        dz += (dz < -hz ? cz : 0.0f) - (dz >= hz ? cz : 0.0f);
        const float dsq = dx * dx + dy * dy + dz * dz;
        if (dsq != 0.0f && dsq < cutsq) {
            const float d    = sqrtf(dsq);
            const int   base = (int)(d * INV_DB) - 7;   // window [base, base+15]
            const float t0   = d - (float)base * DB;
#pragma unroll
            for (int k = 0; k < 16; ++k) {
                const float t = t0 - (float)k * DB;     // k*DB folds to a constant
                const float g = __expf(coeff * t * t);
                const int  bi = base + k;
                if ((unsigned)bi < NBINS) atomicAdd(&sh[bi], g);
            }
        }
    }

    __syncthreads();
    // bin-major partial store: phase-2 loads over p are coalesced
    if (threadIdx.x < NBINS) ws[threadIdx.x * NBLK + blockIdx.x] = sh[threadIdx.x];
    __threadfence();                 // device-scope release (cross-XCD visibility)
    cg::this_grid().sync();

    if (blockIdx.x != 0) return;

    // ---- phase 2, block 0 only ----
    const int t = threadIdx.x;
    if (t < 8 * NBINS) {             // 8 threads per bin
        const int b = t >> 3, sub = t & 7;
        const float* p = &ws[b * NBLK + sub * 32];
        float s0 = 0.f, s1 = 0.f, s2 = 0.f, s3 = 0.f;
#pragma unroll
        for (int k = 0; k < 32; k += 4) {
            s0 += p[k + 0]; s1 += p[k + 1]; s2 += p[k + 2]; s3 += p[k + 3];
        }
        float s = (s0 + s1) + (s2 + s3);
        s += __shfl_xor(s, 1, 64);   // butterfly within the 8-lane group
        s += __shfl_xor(s, 2, 64);
        s += __shfl_xor(s, 4, 64);
        if (sub == 0) tot[b] = s;
    }
    __syncthreads();

    const float v = (t < NBINS) ? tot[t] : 0.0f;
    if (t < 128) {
        float s = v;
        s += __shfl_xor(s, 1, 64);
        s += __shfl_xor(s, 2, 64);
        s += __shfl_xor(s, 4, 64);
        s += __shfl_xor(s, 8, 64);
        s += __shfl_xor(s, 16, 64);
        s += __shfl_xor(s, 32, 64);
        if ((t & 63) == 0) wsum[t >> 6] = s;
    }
    __syncthreads();
    const float total = wsum[0] + wsum[1];

    if (t < NBINS) {
        const float count = v / total;
        out[t] = count;                                   // output 0: count[100]
        const float b0 = 0.05f * (float)t;
        const float b1 = 0.05f * (float)(t + 1);
        const float vol = (4.0f * PI_F / 3.0f) * (b1 * b1 * b1 - b0 * b0 * b0);
        const float V = (4.0f / 3.0f) * PI_F * 125.0f;    // end^3 = 5^3
        out[2 * NBINS + 1 + t] = count * V / vol;         // output 2: rdf[100]
    }
    if (t < NBINS + 1) {
        out[NBINS + t] = 0.05f * (float)t;                // output 1: bins[101]
    }
}

// ---------------- fallback path (R2's proven 3-kernel pipeline) ----------------
__global__ void zero_ws(float* ws) {
    if (threadIdx.x < NBINS) ws[threadIdx.x] = 0.0f;
}

__global__ __launch_bounds__(1024) void rdf_hist(const float* __restrict__ xyz,
                                                 const float* __restrict__ cell,
                                                 float* __restrict__ hist) {
    const float cx = cell[0], cy = cell[1], cz = cell[2];
    const float hx = 0.5f * cx, hy = 0.5f * cy, hz = 0.5f * cz;
    const float coeff  = -0.5f * (99.0f * 99.0f) / (5.0f * 5.0f);
    const float cutsq  = 5.5f * 5.5f;
    const float DB     = 5.0f / 99.0f;
    const float INV_DB = 99.0f / 5.0f;

    __shared__ float sh[NBINS];
    if (threadIdx.x < NBINS) sh[threadIdx.x] = 0.0f;
    __syncthreads();

    const int j = threadIdx.x;
    const float xj = xyz[3 * j + 0];
    const float yj = xyz[3 * j + 1];
    const float zj = xyz[3 * j + 2];

    const int i0 = blockIdx.x * 4;
#pragma unroll
    for (int r = 0; r < 4; ++r) {
        const int i = i0 + r;
        const float xi = xyz[3 * i + 0];
        const float yi = xyz[3 * i + 1];
        const float zi = xyz[3 * i + 2];
        float dx = xj - xi;
        float dy = yj - yi;
        float dz = zj - zi;
        dx += (dx < -hx ? cx : 0.0f) - (dx >= hx ? cx : 0.0f);
        dy += (dy < -hy ? cy : 0.0f) - (dy >= hy ? cy : 0.0f);
        dz += (dz < -hz ? cz : 0.0f) - (dz >= hz ? cz : 0.0f);
        const float dsq = dx * dx + dy * dy + dz * dz;
        if (dsq != 0.0f && dsq < cutsq) {
            const float d    = sqrtf(dsq);
            const int   base = (int)(d * INV_DB) - 7;
            const float t0   = d - (float)base * DB;
#pragma unroll
            for (int k = 0; k < 16; ++k) {
                const float t = t0 - (float)k * DB;
                const float g = __expf(coeff * t * t);
                const int  bi = base + k;
                if ((unsigned)bi < NBINS) atomicAdd(&sh[bi], g);
            }
        }
    }

    __syncthreads();
    if (threadIdx.x < NBINS) atomicAdd(&hist[threadIdx.x], sh[threadIdx.x]);
}

__global__ __launch_bounds__(128) void rdf_finalize(const float* __restrict__ hist,
                                                    float* __restrict__ out) {
    const int t = threadIdx.x;
    const float v = (t < NBINS) ? hist[t] : 0.0f;

    float s = v;
    s += __shfl_xor(s, 1, 64);
    s += __shfl_xor(s, 2, 64);
    s += __shfl_xor(s, 4, 64);
    s += __shfl_xor(s, 8, 64);
    s += __shfl_xor(s, 16, 64);
    s += __shfl_xor(s, 32, 64);

    __shared__ float wsum[2];
    if ((t & 63) == 0) wsum[t >> 6] = s;
    __syncthreads();
    const float total = wsum[0] + wsum[1];

    if (t < NBINS) {
        const float count = v / total;
        out[t] = count;
        const float b0 = 0.05f * (float)t;
        const float b1 = 0.05f * (float)(t + 1);
        const float vol = (4.0f * PI_F / 3.0f) * (b1 * b1 * b1 - b0 * b0 * b0);
        const float V = (4.0f / 3.0f) * PI_F * 125.0f;
        out[2 * NBINS + 1 + t] = count * V / vol;
    }
    if (t < NBINS + 1) {
        out[NBINS + t] = 0.05f * (float)t;
    }
}

extern "C" void kernel_launch(void* const* d_in, const int* in_sizes, int n_in,
                              void* d_out, int out_size, void* d_ws, size_t ws_size,
                              hipStream_t stream) {
    const float* xyz  = (const float*)d_in[0];
    const float* cell = (const float*)d_in[1];
    float* out = (float*)d_out;
    float* ws  = (float*)d_ws;

    void* args[] = {(void*)&xyz, (void*)&cell, (void*)&out, (void*)&ws};
    hipError_t e = hipLaunchCooperativeKernel((const void*)rdf_all,
                                              dim3(NBLK), dim3(1024),
                                              args, 0, stream);
    if (e != hipSuccess) {
        // fallback: proven 3-kernel pipeline
        zero_ws<<<1, 128, 0, stream>>>(ws);
        rdf_hist<<<NBLK, 1024, 0, stream>>>(xyz, cell, ws);
        rdf_finalize<<<1, 128, 0, stream>>>(ws, out);
    }
}

// Round 4
// 27.008 us; speedup vs baseline: 4.7319x; 4.7319x over previous
//
#include <hip/hip_runtime.h>

#define NBINS 100
#define NATOM 1024
#define NBLK  256
#define NWAVE 16
#define PI_F 3.14159265358979323846f

// 256 blocks x 1024 threads; block handles rows i0..i0+3, thread owns column j.
// Windowed Gaussian smear (16 bins around floor(d/DB); omitted tail < 2e-11/pair)
// into per-wave LDS histograms. Block partials -> ws[bin*NBLK + block].
// No global atomics, no pre-zero needed: every ws location read later is written here.
__global__ __launch_bounds__(1024) void rdf_hist(const float* __restrict__ xyz,
                                                 const float* __restrict__ cell,
                                                 float* __restrict__ ws) {
    const float cx = cell[0], cy = cell[1], cz = cell[2];
    const float hx = 0.5f * cx, hy = 0.5f * cy, hz = 0.5f * cz;
    const float coeff  = -0.5f * (99.0f * 99.0f) / (5.0f * 5.0f);  // -0.5/width^2
    const float cutsq  = 5.5f * 5.5f;
    const float DB     = 5.0f / 99.0f;
    const float INV_DB = 99.0f / 5.0f;

    __shared__ float shw[NWAVE][NBINS];
    for (int k = threadIdx.x; k < NWAVE * NBINS; k += 1024)
        (&shw[0][0])[k] = 0.0f;
    __syncthreads();

    const int wave = threadIdx.x >> 6;

    // thread owns atom j (coalesced load)
    const int j = threadIdx.x;
    const float xj = xyz[3 * j + 0];
    const float yj = xyz[3 * j + 1];
    const float zj = xyz[3 * j + 2];

    const int i0 = blockIdx.x * (NATOM / NBLK);
#pragma unroll
    for (int r = 0; r < NATOM / NBLK; ++r) {
        const int i = i0 + r;                 // block-uniform -> scalar loads
        const float xi = xyz[3 * i + 0];
        const float yi = xyz[3 * i + 1];
        const float zi = xyz[3 * i + 2];
        float dx = xj - xi;                   // dvec = xyz[j] - xyz[i]
        float dy = yj - yi;
        float dz = zj - zi;
        // minimum-image PBC, exact replication of reference shift rule
        dx += (dx < -hx ? cx : 0.0f) - (dx >= hx ? cx : 0.0f);
        dy += (dy < -hy ? cy : 0.0f) - (dy >= hy ? cy : 0.0f);
        dz += (dz < -hz ? cz : 0.0f) - (dz >= hz ? cz : 0.0f);
        const float dsq = dx * dx + dy * dy + dz * dz;
        if (dsq != 0.0f && dsq < cutsq) {
            const float d    = sqrtf(dsq);
            const int   base = (int)(d * INV_DB) - 7;   // window [base, base+15]
            const float t0   = d - (float)base * DB;
#pragma unroll
            for (int k = 0; k < 16; ++k) {
                const float t = t0 - (float)k * DB;     // k*DB folds to a constant
                const float g = __expf(coeff * t * t);
                const int  bi = base + k;
                if ((unsigned)bi < NBINS) atomicAdd(&shw[wave][bi], g);
            }
        }
    }

    __syncthreads();
    if (threadIdx.x < NBINS) {
        float s = 0.0f;
#pragma unroll
        for (int w = 0; w < NWAVE; ++w) s += shw[w][threadIdx.x];
        // bin-major partial store: finalize's loads over blocks are coalesced
        ws[threadIdx.x * NBLK + blockIdx.x] = s;
    }
}

// single block, 1024 threads: reduce 256 partials/bin, normalize, emit outputs
__global__ __launch_bounds__(1024) void rdf_finalize(const float* __restrict__ ws,
                                                     float* __restrict__ out) {
    __shared__ float tot[NBINS];
    __shared__ float wsum[2];

    const int t = threadIdx.x;
    if (t < 8 * NBINS) {             // 8 threads per bin
        const int b = t >> 3, sub = t & 7;
        const float* p = &ws[b * NBLK + sub * 32];
        float s0 = 0.f, s1 = 0.f, s2 = 0.f, s3 = 0.f;
#pragma unroll
        for (int k = 0; k < 32; k += 4) {
            s0 += p[k + 0]; s1 += p[k + 1]; s2 += p[k + 2]; s3 += p[k + 3];
        }
        float s = (s0 + s1) + (s2 + s3);
        s += __shfl_xor(s, 1, 64);   // butterfly within the 8-lane group
        s += __shfl_xor(s, 2, 64);
        s += __shfl_xor(s, 4, 64);
        if (sub == 0) tot[b] = s;
    }
    __syncthreads();

    const float v = (t < NBINS) ? tot[t] : 0.0f;
    if (t < 128) {
        float s = v;
        s += __shfl_xor(s, 1, 64);
        s += __shfl_xor(s, 2, 64);
        s += __shfl_xor(s, 4, 64);
        s += __shfl_xor(s, 8, 64);
        s += __shfl_xor(s, 16, 64);
        s += __shfl_xor(s, 32, 64);
        if ((t & 63) == 0) wsum[t >> 6] = s;
    }
    __syncthreads();
    const float total = wsum[0] + wsum[1];

    if (t < NBINS) {
        const float count = v / total;
        out[t] = count;                                   // output 0: count[100]
        const float b0 = 0.05f * (float)t;
        const float b1 = 0.05f * (float)(t + 1);
        const float vol = (4.0f * PI_F / 3.0f) * (b1 * b1 * b1 - b0 * b0 * b0);
        const float V = (4.0f / 3.0f) * PI_F * 125.0f;    // end^3 = 5^3
        out[2 * NBINS + 1 + t] = count * V / vol;         // output 2: rdf[100]
    }
    if (t < NBINS + 1) {
        out[NBINS + t] = 0.05f * (float)t;                // output 1: bins[101]
    }
}

extern "C" void kernel_launch(void* const* d_in, const int* in_sizes, int n_in,
                              void* d_out, int out_size, void* d_ws, size_t ws_size,
                              hipStream_t stream) {
    const float* xyz  = (const float*)d_in[0];
    const float* cell = (const float*)d_in[1];
    float* out = (float*)d_out;
    float* ws  = (float*)d_ws;

    rdf_hist<<<NBLK, 1024, 0, stream>>>(xyz, cell, ws);
    rdf_finalize<<<1, 1024, 0, stream>>>(ws, out);
}